// Round 2
// baseline (755.141 us; speedup 1.0000x reference)
//
#include <hip/hip_runtime.h>
#include <hip/hip_bf16.h>

#define B_ 128
#define L_ 1024
#define T_ 512   // L/2 tokens per parity
#define D_ 768
#define CH_ 96   // D/8 chunks of 8 elems
#define DT_ 513  // output tokens per batch
#define TAU 5e-5f

typedef __attribute__((ext_vector_type(8))) short bf16x8;
typedef __attribute__((ext_vector_type(4))) float f32x4;

__device__ __forceinline__ unsigned short f2bf_rne(float x){
    unsigned u = __float_as_uint(x);
    unsigned r = (u + 0x7FFFu + ((u >> 16) & 1u)) >> 16;
    return (unsigned short)r;
}
__device__ __forceinline__ float bf2f(unsigned short h){
    return __uint_as_float(((unsigned)h) << 16);
}

// ---------------- norms: fp64-accurate 1/|x| and |x|^2 ----------------
__global__ __launch_bounds__(256) void norms_k(const float* __restrict__ hs,
                                               float* __restrict__ rnorm,
                                               double* __restrict__ nsq){
    int wave = threadIdx.x >> 6, lane = threadIdx.x & 63;
    long row = (long)blockIdx.x * 4 + wave;           // < B*L
    const float* p = hs + row * D_;
    double s = 0.0;
    #pragma unroll
    for (int dd = 0; dd < 12; ++dd){
        float v = p[dd * 64 + lane];
        s += (double)v * (double)v;
    }
    #pragma unroll
    for (int off = 32; off; off >>= 1) s += __shfl_xor(s, off);
    if (lane == 0){
        nsq[row] = s;
        rnorm[row] = (float)(1.0 / sqrt(s));
    }
}

// ---------------- pack B (odd tokens): normalized hi/lo bf16, chunk-major ----------------
// layout: Bh[((b*96 + c)*512 + j)*8 + e]  (c = k-chunk of 8, j = odd-token index)
__global__ __launch_bounds__(256) void pack_k(const float* __restrict__ hs,
                                              const float* __restrict__ rnorm,
                                              unsigned short* __restrict__ Bh,
                                              unsigned short* __restrict__ Bl){
    int gid = blockIdx.x * 256 + threadIdx.x;   // < 128*96*512
    int j = gid & 511;
    int rest = gid >> 9;
    int c = rest % CH_;
    int b = rest / CH_;
    long seq = (long)b * L_ + 2 * j + 1;
    const float* src = hs + seq * D_ + c * 8;
    float rn = rnorm[seq];
    float4 x0 = ((const float4*)src)[0];
    float4 x1 = ((const float4*)src)[1];
    float v[8] = {x0.x, x0.y, x0.z, x0.w, x1.x, x1.y, x1.z, x1.w};
    bf16x8 hv, lv;
    #pragma unroll
    for (int e = 0; e < 8; ++e){
        float a = v[e] * rn;
        unsigned short h = f2bf_rne(a);
        unsigned short l = f2bf_rne(a - bf2f(h));
        hv[e] = (short)h; lv[e] = (short)l;
    }
    long o = ((long)(b * CH_ + c) * T_ + j) * 8;
    *(bf16x8*)(Bh + o) = hv;
    *(bf16x8*)(Bl + o) = lv;
}

// ---------------- scores: A on-the-fly split (LDS, dbuf), B from packed, fused argmax ----------------
// block tile: 64 A-rows (it 0..7) x 256 B-cols (jt 0..1); 4 waves, wave wv owns cols wv*64..+63.
__global__ __launch_bounds__(256, 2) void scores_k(const float* __restrict__ hs,
                                                   const float* __restrict__ rnorm,
                                                   const unsigned short* __restrict__ Bh,
                                                   const unsigned short* __restrict__ Bl,
                                                   float* __restrict__ pmax1,
                                                   int*   __restrict__ pj1,
                                                   float* __restrict__ pmax2){
    __shared__ __align__(16) unsigned short Ah[2][4][64][8];  // [buf][oct][row][e] 8KB
    __shared__ __align__(16) unsigned short Al[2][4][64][8];  // 8KB
    __shared__ float pm1s[64][4];
    __shared__ float pm2s[64][4];
    __shared__ int   pjs[64][4];

    int bid = blockIdx.x;                 // 2048 blocks
    int xcd = bid & 7, q = bid >> 3;
    int b = (xcd << 4) | (q & 15);        // same-b blocks land on same XCD
    int r2 = q >> 4;                      // 0..15
    int it = r2 >> 1, jt = r2 & 1;

    int tid = threadIdx.x;
    int wv = tid >> 6, lane = tid & 63, l15 = lane & 15, l4 = lane >> 4;

    // A staging mapping: thread -> (row, k-octet)
    int rowA = tid >> 2, oct = tid & 3;
    int iA = it * 64 + rowA;
    const float* gA = hs + ((long)b * L_ + 2 * iA) * D_ + oct * 8;
    float rnA = rnorm[b * L_ + 2 * iA];

    // B fragment per-lane base (shorts)
    int jB = jt * 256 + wv * 64 + l15;
    long bbase = ((long)(b * CH_ + l4) * T_ + jB) * 8;
    const unsigned short* pBh = Bh + bbase;
    const unsigned short* pBl = Bl + bbase;

    f32x4 acc[4][4];
    #pragma unroll
    for (int i = 0; i < 4; ++i)
        #pragma unroll
        for (int j = 0; j < 4; ++j) acc[i][j] = (f32x4){0.f, 0.f, 0.f, 0.f};

    float4 x0 = ((const float4*)gA)[0];
    float4 x1 = ((const float4*)gA)[1];

    for (int s = 0; s < 24; ++s){
        int buf = s & 1;
        { // convert + LDS write (conflict-free b128 pattern)
            float v[8] = {x0.x, x0.y, x0.z, x0.w, x1.x, x1.y, x1.z, x1.w};
            bf16x8 hv, lv;
            #pragma unroll
            for (int e = 0; e < 8; ++e){
                float a = v[e] * rnA;
                unsigned short h = f2bf_rne(a);
                unsigned short l = f2bf_rne(a - bf2f(h));
                hv[e] = (short)h; lv[e] = (short)l;
            }
            *(bf16x8*)&Ah[buf][oct][rowA][0] = hv;
            *(bf16x8*)&Al[buf][oct][rowA][0] = lv;
        }
        __syncthreads();
        if (s < 23){ // prefetch next A raw floats (latency hidden under MFMA)
            const float4* g = (const float4*)(gA + (s + 1) * 32);
            x0 = g[0]; x1 = g[1];
        }
        bf16x8 bh[4], bl[4];
        #pragma unroll
        for (int jb = 0; jb < 4; ++jb){
            bh[jb] = *(const bf16x8*)(pBh + jb * 128);
            bl[jb] = *(const bf16x8*)(pBl + jb * 128);
        }
        pBh += 4 * T_ * 8;
        pBl += 4 * T_ * 8;
        bf16x8 ah[4], al[4];
        #pragma unroll
        for (int ib = 0; ib < 4; ++ib){
            ah[ib] = *(const bf16x8*)&Ah[buf][l4][ib * 16 + l15][0];
            al[ib] = *(const bf16x8*)&Al[buf][l4][ib * 16 + l15][0];
        }
        #pragma unroll
        for (int ib = 0; ib < 4; ++ib)
            #pragma unroll
            for (int jb = 0; jb < 4; ++jb){
                acc[ib][jb] = __builtin_amdgcn_mfma_f32_16x16x32_bf16(ah[ib], bh[jb], acc[ib][jb], 0, 0, 0);
                acc[ib][jb] = __builtin_amdgcn_mfma_f32_16x16x32_bf16(ah[ib], bl[jb], acc[ib][jb], 0, 0, 0);
                acc[ib][jb] = __builtin_amdgcn_mfma_f32_16x16x32_bf16(al[ib], bh[jb], acc[ib][jb], 0, 0, 0);
            }
    }

    // epilogue: per-row max1/argmax/max2 via register butterfly
    // C layout: row = ib*16 + l4*4 + rr, col = jt*256 + wv*64 + jb*16 + l15
    #pragma unroll
    for (int ib = 0; ib < 4; ++ib)
        #pragma unroll
        for (int rr = 0; rr < 4; ++rr){
            float m1 = -1e30f, m2 = -1e30f; int j1 = 0;
            #pragma unroll
            for (int jb = 0; jb < 4; ++jb){   // ascending cols: strict > keeps lowest j
                float v2 = acc[ib][jb][rr];
                int col = jt * 256 + wv * 64 + jb * 16 + l15;
                if (v2 > m1){ m2 = m1; m1 = v2; j1 = col; }
                else m2 = fmaxf(m2, v2);
            }
            #pragma unroll
            for (int m = 1; m < 16; m <<= 1){
                float o1 = __shfl_xor(m1, m);
                float o2 = __shfl_xor(m2, m);
                int   oj = __shfl_xor(j1, m);
                if (o1 > m1){ m2 = fmaxf(m1, o2); m1 = o1; j1 = oj; }
                else if (o1 < m1){ m2 = fmaxf(m2, o1); }
                else { m2 = m1; j1 = min(j1, oj); }   // exact tie -> margin 0 -> rescued
            }
            if (l15 == 0){
                int row = ib * 16 + l4 * 4 + rr;
                pm1s[row][wv] = m1; pm2s[row][wv] = m2; pjs[row][wv] = j1;
            }
        }
    __syncthreads();
    if (tid < 64){
        float M1 = -1e30f, M2 = -1e30f; int J1 = 0;
        #pragma unroll
        for (int w2 = 0; w2 < 4; ++w2){    // ascending col blocks: ties keep lower j
            float a1 = pm1s[tid][w2], a2 = pm2s[tid][w2]; int aj = pjs[tid][w2];
            if (a1 > M1){ M2 = fmaxf(M1, a2); M1 = a1; J1 = aj; }
            else M2 = fmaxf(M2, a1);
        }
        long idx = ((long)b * T_ + it * 64 + tid) * 2 + jt;
        pmax1[idx] = M1; pmax2[idx] = M2; pj1[idx] = J1;
    }
}

// ---------------- reduce partials, flag borderline rows ----------------
__global__ __launch_bounds__(256) void reduce_k(const float* __restrict__ pmax1,
                                                const int*   __restrict__ pj1,
                                                const float* __restrict__ pmax2,
                                                int* __restrict__ node_idx,
                                                int* __restrict__ flagcnt,
                                                int* __restrict__ flaglist){
    int t = blockIdx.x * 256 + threadIdx.x;
    if (t >= B_ * T_) return;
    float M1 = -1e30f, M2 = -1e30f; int J1 = -1;
    #pragma unroll
    for (int p = 0; p < 2; ++p){   // ascending jt: lowest-j tie rule preserved
        float a1 = pmax1[(long)t * 2 + p], a2 = pmax2[(long)t * 2 + p];
        int aj = pj1[(long)t * 2 + p];
        if (a1 > M1){ M2 = fmaxf(M1, a2); M1 = a1; J1 = aj; }
        else M2 = fmaxf(M2, a1);
    }
    node_idx[t] = J1;
    int i = t & (T_ - 1);
    if (i != 0 && (M1 - M2) < TAU){
        int p = atomicAdd(flagcnt, 1);
        flaglist[p] = t;
    }
}

// ---------------- fp64 exact rescore of flagged rows ----------------
__global__ __launch_bounds__(256) void exact_k(const float* __restrict__ hs,
                                               const double* __restrict__ nsq,
                                               const int* __restrict__ flagcnt,
                                               const int* __restrict__ flaglist,
                                               int* __restrict__ node_idx){
    __shared__ float arow[D_];
    __shared__ double wbv[4];
    __shared__ int wbj[4];
    int nf = *flagcnt;
    for (int f = blockIdx.x; f < nf; f += gridDim.x){
        __syncthreads();
        int t = flaglist[f];
        int b = t >> 9, i = t & 511;
        for (int d = threadIdx.x; d < D_; d += 256)
            arow[d] = hs[((long)b * L_ + 2 * i) * D_ + d];
        __syncthreads();
        int wv = threadIdx.x >> 6, lane = threadIdx.x & 63;
        double bv = -1e300; int bj = -1;
        for (int j = wv; j < T_; j += 4){
            const float* brow = hs + ((long)b * L_ + 2 * j + 1) * D_;
            double s = 0.0;
            #pragma unroll
            for (int dd = 0; dd < 12; ++dd){
                int d = dd * 64 + lane;
                s += (double)arow[d] * (double)brow[d];
            }
            #pragma unroll
            for (int off = 32; off; off >>= 1) s += __shfl_xor(s, off);
            double sc = s / sqrt(nsq[(long)b * L_ + 2 * j + 1]); // row-uniform 1/|a_i| dropped
            if (sc > bv){ bv = sc; bj = j; }
        }
        if (lane == 0){ wbv[wv] = bv; wbj[wv] = bj; }
        __syncthreads();
        if (threadIdx.x == 0){
            double BV = -1e300; int BJ = 1 << 30;
            #pragma unroll
            for (int w2 = 0; w2 < 4; ++w2)
                if (wbv[w2] > BV || (wbv[w2] == BV && wbj[w2] < BJ)){ BV = wbv[w2]; BJ = wbj[w2]; }
            node_idx[t] = BJ;
        }
        __syncthreads();
    }
}

// ---------------- deterministic CSR (stable by source index) ----------------
__global__ __launch_bounds__(512) void csr_k(const int* __restrict__ node_idx,
                                             int* __restrict__ goff,
                                             int* __restrict__ glist){
    __shared__ int sidx[512];
    __shared__ int off[513];
    __shared__ int tmp[512];
    int b = blockIdx.x, t = threadIdx.x;
    sidx[t] = node_idx[b * T_ + t];
    __shared__ int cnt[512];
    cnt[t] = 0;
    __syncthreads();
    if (t >= 1) atomicAdd(&cnt[sidx[t]], 1);   // i=0 excluded (always unmerged)
    __syncthreads();
    tmp[t] = cnt[t];
    __syncthreads();
    for (int s = 1; s < 512; s <<= 1){
        int v = (t >= s) ? tmp[t - s] : 0;
        __syncthreads();
        tmp[t] += v;
        __syncthreads();
    }
    if (t == 0) off[0] = 0;
    off[t + 1] = tmp[t];
    __syncthreads();
    if (t >= 1){
        int j = sidx[t], r = 0;
        for (int i2 = 1; i2 < t; ++i2) r += (sidx[i2] == j);  // stable rank
        glist[b * T_ + off[j] + r] = t;
    }
    goff[b * 513 + t] = off[t];
    if (t == 0) goff[b * 513 + 512] = off[512];
}

// ---------------- merge: gather sources per dst, mean, write ----------------
__global__ __launch_bounds__(256) void merge_k(const float* __restrict__ hs,
                                               const int* __restrict__ goff,
                                               const int* __restrict__ glist,
                                               float* __restrict__ out){
    int bid = blockIdx.x;
    int b = bid / DT_, jj = bid - b * DT_;
    long obase = ((long)b * DT_ + jj) * D_;
    int d0 = threadIdx.x, d1 = d0 + 256, d2 = d0 + 512;
    if (jj == 0){  // unmerged token = src[0] = seq 0
        const float* src = hs + (long)b * L_ * D_;
        out[obase + d0] = src[d0]; out[obase + d1] = src[d1]; out[obase + d2] = src[d2];
        return;
    }
    int j = jj - 1;
    int o0 = goff[b * 513 + j], o1 = goff[b * 513 + j + 1];
    const float* dst = hs + ((long)b * L_ + 2 * j + 1) * D_;
    float a0 = dst[d0], a1 = dst[d1], a2 = dst[d2];
    for (int s = o0; s < o1; ++s){   // ascending source index: deterministic
        int i = glist[b * T_ + s];
        const float* srow = hs + ((long)b * L_ + 2 * i) * D_;
        a0 += srow[d0]; a1 += srow[d1]; a2 += srow[d2];
    }
    float cnt = (float)(o1 - o0 + 1);
    out[obase + d0] = a0 / cnt;
    out[obase + d1] = a1 / cnt;
    out[obase + d2] = a2 / cnt;
}

__global__ __launch_bounds__(256) void mask_k(float* __restrict__ out){
    int t = blockIdx.x * 256 + threadIdx.x;
    if (t < B_ * DT_) out[(long)B_ * DT_ * D_ + t] = 0.0f;
}

extern "C" void kernel_launch(void* const* d_in, const int* in_sizes, int n_in,
                              void* d_out, int out_size, void* d_ws, size_t ws_size,
                              hipStream_t stream){
    const float* hs = (const float*)d_in[0];  // (128,1024,768) f32
    float* out = (float*)d_out;
    char* ws = (char*)d_ws;

    // packed B (hi/lo) lives in d_out as scratch until merge_k overwrites it:
    // 2 * 128*96*512*8 shorts = 201.3 MB <= out bytes (202.0 MB)
    unsigned short* Bh = (unsigned short*)d_out;
    unsigned short* Bl = Bh + (long)B_ * CH_ * T_ * 8;

    float*  rnorm    = (float*) (ws + 0);         // 524288 B
    double* nsq      = (double*)(ws + 524288);    // 1048576 B
    float*  pmax1    = (float*) (ws + 1572864);   // 524288 B (B*T*2)
    int*    pj1      = (int*)   (ws + 2097152);   // 524288 B
    float*  pmax2    = (float*) (ws + 2621440);   // 524288 B
    int*    node_idx = (int*)   (ws + 3145728);   // 262144 B
    int*    flagcnt  = (int*)   (ws + 3407872);   // 256 B
    int*    flaglist = (int*)   (ws + 3408128);   // 262144 B
    int*    goff     = (int*)   (ws + 3670272);   // 263168 B
    int*    glist    = (int*)   (ws + 3933440);   // 262144 B  -> total ~4.2 MB

    hipMemsetAsync(flagcnt, 0, 4, stream);
    norms_k <<<B_ * L_ / 4, 256, 0, stream>>>(hs, rnorm, nsq);
    pack_k  <<<B_ * CH_ * T_ / 256, 256, 0, stream>>>(hs, rnorm, Bh, Bl);
    scores_k<<<B_ * 16, 256, 0, stream>>>(hs, rnorm, Bh, Bl, pmax1, pj1, pmax2);
    reduce_k<<<B_ * T_ / 256, 256, 0, stream>>>(pmax1, pj1, pmax2, node_idx, flagcnt, flaglist);
    exact_k <<<256, 256, 0, stream>>>(hs, nsq, flagcnt, flaglist, node_idx);
    csr_k   <<<B_, 512, 0, stream>>>(node_idx, goff, glist);
    merge_k <<<B_ * DT_, 256, 0, stream>>>(hs, goff, glist, out);
    mask_k  <<<(B_ * DT_ + 255) / 256, 256, 0, stream>>>(out);
}

// Round 3
// 652.899 us; speedup vs baseline: 1.1566x; 1.1566x over previous
//
#include <hip/hip_runtime.h>
#include <hip/hip_bf16.h>

#define B_ 128
#define L_ 1024
#define T_ 512   // L/2 tokens per parity
#define D_ 768
#define CH_ 96   // D/8 chunks of 8 elems
#define DT_ 513  // output tokens per batch
#define TAU 5e-5f

typedef __attribute__((ext_vector_type(8))) short bf16x8;
typedef __attribute__((ext_vector_type(4))) float f32x4;

__device__ __forceinline__ unsigned short f2bf_rne(float x){
    unsigned u = __float_as_uint(x);
    unsigned r = (u + 0x7FFFu + ((u >> 16) & 1u)) >> 16;
    return (unsigned short)r;
}
__device__ __forceinline__ float bf2f(unsigned short h){
    return __uint_as_float(((unsigned)h) << 16);
}

// ---------------- norms (EVEN rows only): fp64-accurate 1/|x| ----------------
__global__ __launch_bounds__(256) void norms_k(const float* __restrict__ hs,
                                               float* __restrict__ rnorm,
                                               int* __restrict__ flagcnt){
    if (blockIdx.x == 0 && threadIdx.x == 0) *flagcnt = 0;  // replaces hipMemsetAsync
    int wave = threadIdx.x >> 6, lane = threadIdx.x & 63;
    int r = blockIdx.x * 4 + wave;            // < B*T (even-token index)
    int b = r >> 9, i = r & 511;
    long seq = (long)b * L_ + 2 * i;
    const float* p = hs + seq * D_;
    double s = 0.0;
    #pragma unroll
    for (int dd = 0; dd < 12; ++dd){
        float v = p[dd * 64 + lane];
        s += (double)v * (double)v;
    }
    #pragma unroll
    for (int off = 32; off; off >>= 1) s += __shfl_xor(s, off);
    if (lane == 0) rnorm[seq] = (float)(1.0 / sqrt(s));
}

// ---------------- pack B (odd tokens): norm (fp64) + hi/lo bf16 split, chunk-major ----------------
// LDS-transposed: coalesced row reads, 256B-segment chunk-major writes.
// global layout: Bh[((b*96 + c)*512 + j)*8 + e]
__global__ __launch_bounds__(256) void pack_k(const float* __restrict__ hs,
                                              unsigned short* __restrict__ Bh,
                                              unsigned short* __restrict__ Bl,
                                              double* __restrict__ nsq){
    __shared__ __align__(16) unsigned short LhS[CH_ * 16 * 8];  // 24.6 KB
    __shared__ __align__(16) unsigned short LlS[CH_ * 16 * 8];
    int b = blockIdx.x >> 5, g = blockIdx.x & 31;   // 16 odd tokens per block
    int wv = threadIdx.x >> 6, lane = threadIdx.x & 63;

    #pragma unroll
    for (int rr = 0; rr < 4; ++rr){
        int jj = wv * 4 + rr;                       // 0..15 within block
        int j = g * 16 + jj;
        long seq = (long)b * L_ + 2 * j + 1;
        const float4* src = (const float4*)(hs + seq * D_);
        float4 f0 = src[lane], f1 = src[lane + 64], f2 = src[lane + 128];
        double s = 0.0;
        s += (double)f0.x*f0.x + (double)f0.y*f0.y + (double)f0.z*f0.z + (double)f0.w*f0.w;
        s += (double)f1.x*f1.x + (double)f1.y*f1.y + (double)f1.z*f1.z + (double)f1.w*f1.w;
        s += (double)f2.x*f2.x + (double)f2.y*f2.y + (double)f2.z*f2.z + (double)f2.w*f2.w;
        #pragma unroll
        for (int off = 32; off; off >>= 1) s += __shfl_xor(s, off);
        if (lane == 0) nsq[seq] = s;
        float rn = (float)(1.0 / sqrt(s));
        float4 fv[3] = {f0, f1, f2};
        #pragma unroll
        for (int t = 0; t < 3; ++t){
            int e0 = t * 256 + lane * 4;
            int c = e0 >> 3, ei = e0 & 7;           // ei = 0 or 4
            float vv[4] = {fv[t].x, fv[t].y, fv[t].z, fv[t].w};
            short4 hv, lv;
            #pragma unroll
            for (int e = 0; e < 4; ++e){
                float a = vv[e] * rn;
                unsigned short h = f2bf_rne(a);
                unsigned short l = f2bf_rne(a - bf2f(h));
                ((short*)&hv)[e] = (short)h; ((short*)&lv)[e] = (short)l;
            }
            int o = c * 128 + ((jj ^ (c & 7)) << 3) + ei;   // XOR-swizzled (shorts)
            *(short4*)(LhS + o) = hv;
            *(short4*)(LlS + o) = lv;
        }
    }
    __syncthreads();
    // write out: 1536 b128 per array; 16 consecutive jj -> 256B contiguous global segments
    #pragma unroll
    for (int it = 0; it < 6; ++it){
        int linear = it * 256 + threadIdx.x;
        int c = linear >> 4, jj = linear & 15;
        int o = c * 128 + ((jj ^ (c & 7)) << 3);
        long go = ((long)(b * CH_ + c) * T_ + g * 16 + jj) * 8;
        *(bf16x8*)(Bh + go) = *(const bf16x8*)(LhS + o);
        *(bf16x8*)(Bl + go) = *(const bf16x8*)(LlS + o);
    }
}

// ---------------- scores: pipelined (B regs dbuf, A LDS dbuf), fused argmax ----------------
// block tile: 64 A-rows x 256 B-cols; wave wv owns cols wv*64..+63.
__global__ __launch_bounds__(256, 2) void scores_k(const float* __restrict__ hs,
                                                   const float* __restrict__ rnorm,
                                                   const unsigned short* __restrict__ Bh,
                                                   const unsigned short* __restrict__ Bl,
                                                   float* __restrict__ pmax1,
                                                   int*   __restrict__ pj1,
                                                   float* __restrict__ pmax2){
    __shared__ __align__(16) unsigned short Ah[2][4][64][8];  // 8KB
    __shared__ __align__(16) unsigned short Al[2][4][64][8];  // 8KB
    __shared__ float pm1s[64][4];
    __shared__ float pm2s[64][4];
    __shared__ int   pjs[64][4];

    int bid = blockIdx.x;                 // 2048 blocks
    int xcd = bid & 7, q = bid >> 3;
    int b = (xcd << 4) | (q & 15);        // same-b blocks share an XCD L2
    int r2 = q >> 4;
    int it = r2 >> 1, jt = r2 & 1;

    int tid = threadIdx.x;
    int wv = tid >> 6, lane = tid & 63, l15 = lane & 15, l4 = lane >> 4;

    int rowA = tid >> 2, oct = tid & 3;
    int iA = it * 64 + rowA;
    const float* gA = hs + ((long)b * L_ + 2 * iA) * D_ + oct * 8;
    float rnA = rnorm[b * L_ + 2 * iA];

    int jB = jt * 256 + wv * 64 + l15;
    const unsigned short* pBh0 = Bh + ((long)(b * CH_ + l4) * T_ + jB) * 8;
    const unsigned short* pBl0 = Bl + ((long)(b * CH_ + l4) * T_ + jB) * 8;

    f32x4 acc[4][4];
    #pragma unroll
    for (int i = 0; i < 4; ++i)
        #pragma unroll
        for (int j = 0; j < 4; ++j) acc[i][j] = (f32x4){0.f, 0.f, 0.f, 0.f};

    // prologue: A[0] floats -> convert -> LDS buf0; B[0] frags -> regs
    float4 x0 = ((const float4*)gA)[0];
    float4 x1 = ((const float4*)gA)[1];
    {
        float v[8] = {x0.x, x0.y, x0.z, x0.w, x1.x, x1.y, x1.z, x1.w};
        bf16x8 hv, lv;
        #pragma unroll
        for (int e = 0; e < 8; ++e){
            float a = v[e] * rnA;
            unsigned short h = f2bf_rne(a);
            unsigned short l = f2bf_rne(a - bf2f(h));
            hv[e] = (short)h; lv[e] = (short)l;
        }
        *(bf16x8*)&Ah[0][oct][rowA][0] = hv;
        *(bf16x8*)&Al[0][oct][rowA][0] = lv;
    }
    bf16x8 bhc[4], blc[4];
    #pragma unroll
    for (int jb = 0; jb < 4; ++jb){
        bhc[jb] = *(const bf16x8*)(pBh0 + jb * 128);
        blc[jb] = *(const bf16x8*)(pBl0 + jb * 128);
    }
    __syncthreads();

    for (int s = 0; s < 24; ++s){
        int buf = s & 1;
        bf16x8 bhn[4], bln[4];
        float4 x0n, x1n;
        if (s < 23){                       // issue next-step loads early
            long adv = (long)(s + 1) * (4 * T_ * 8);
            #pragma unroll
            for (int jb = 0; jb < 4; ++jb){
                bhn[jb] = *(const bf16x8*)(pBh0 + adv + jb * 128);
                bln[jb] = *(const bf16x8*)(pBl0 + adv + jb * 128);
            }
            const float4* g = (const float4*)(gA + (s + 1) * 32);
            x0n = g[0]; x1n = g[1];
        }
        bf16x8 ah[4], al[4];
        #pragma unroll
        for (int ib = 0; ib < 4; ++ib){
            ah[ib] = *(const bf16x8*)&Ah[buf][l4][ib * 16 + l15][0];
            al[ib] = *(const bf16x8*)&Al[buf][l4][ib * 16 + l15][0];
        }
        // pass-major MFMA: per-acc order (hh, hl, lh) preserved -> bit-identical
        #pragma unroll
        for (int ib = 0; ib < 4; ++ib)
            #pragma unroll
            for (int jb = 0; jb < 4; ++jb)
                acc[ib][jb] = __builtin_amdgcn_mfma_f32_16x16x32_bf16(ah[ib], bhc[jb], acc[ib][jb], 0, 0, 0);
        #pragma unroll
        for (int ib = 0; ib < 4; ++ib)
            #pragma unroll
            for (int jb = 0; jb < 4; ++jb)
                acc[ib][jb] = __builtin_amdgcn_mfma_f32_16x16x32_bf16(ah[ib], blc[jb], acc[ib][jb], 0, 0, 0);
        #pragma unroll
        for (int ib = 0; ib < 4; ++ib)
            #pragma unroll
            for (int jb = 0; jb < 4; ++jb)
                acc[ib][jb] = __builtin_amdgcn_mfma_f32_16x16x32_bf16(al[ib], bhc[jb], acc[ib][jb], 0, 0, 0);
        if (s < 23){                       // convert next A, write other LDS buffer
            float v[8] = {x0n.x, x0n.y, x0n.z, x0n.w, x1n.x, x1n.y, x1n.z, x1n.w};
            bf16x8 hv, lv;
            #pragma unroll
            for (int e = 0; e < 8; ++e){
                float a = v[e] * rnA;
                unsigned short h = f2bf_rne(a);
                unsigned short l = f2bf_rne(a - bf2f(h));
                hv[e] = (short)h; lv[e] = (short)l;
            }
            *(bf16x8*)&Ah[buf ^ 1][oct][rowA][0] = hv;
            *(bf16x8*)&Al[buf ^ 1][oct][rowA][0] = lv;
        }
        __syncthreads();
        #pragma unroll
        for (int jb = 0; jb < 4; ++jb){ bhc[jb] = bhn[jb]; blc[jb] = bln[jb]; }
    }

    // epilogue: per-row max1/argmax/max2 via register butterfly
    #pragma unroll
    for (int ib = 0; ib < 4; ++ib)
        #pragma unroll
        for (int rr = 0; rr < 4; ++rr){
            float m1 = -1e30f, m2 = -1e30f; int j1 = 0;
            #pragma unroll
            for (int jb = 0; jb < 4; ++jb){
                float v2 = acc[ib][jb][rr];
                int col = jt * 256 + wv * 64 + jb * 16 + l15;
                if (v2 > m1){ m2 = m1; m1 = v2; j1 = col; }
                else m2 = fmaxf(m2, v2);
            }
            #pragma unroll
            for (int m = 1; m < 16; m <<= 1){
                float o1 = __shfl_xor(m1, m);
                float o2 = __shfl_xor(m2, m);
                int   oj = __shfl_xor(j1, m);
                if (o1 > m1){ m2 = fmaxf(m1, o2); m1 = o1; j1 = oj; }
                else if (o1 < m1){ m2 = fmaxf(m2, o1); }
                else { m2 = m1; j1 = min(j1, oj); }
            }
            if (l15 == 0){
                int row = ib * 16 + l4 * 4 + rr;
                pm1s[row][wv] = m1; pm2s[row][wv] = m2; pjs[row][wv] = j1;
            }
        }
    __syncthreads();
    if (tid < 64){
        float M1 = -1e30f, M2 = -1e30f; int J1 = 0;
        #pragma unroll
        for (int w2 = 0; w2 < 4; ++w2){
            float a1 = pm1s[tid][w2], a2 = pm2s[tid][w2]; int aj = pjs[tid][w2];
            if (a1 > M1){ M2 = fmaxf(M1, a2); M1 = a1; J1 = aj; }
            else M2 = fmaxf(M2, a1);
        }
        long idx = ((long)b * T_ + it * 64 + tid) * 2 + jt;
        pmax1[idx] = M1; pmax2[idx] = M2; pj1[idx] = J1;
    }
}

// ---------------- reduce partials, flag borderline rows ----------------
__global__ __launch_bounds__(256) void reduce_k(const float* __restrict__ pmax1,
                                                const int*   __restrict__ pj1,
                                                const float* __restrict__ pmax2,
                                                int* __restrict__ node_idx,
                                                int* __restrict__ flagcnt,
                                                int* __restrict__ flaglist){
    int t = blockIdx.x * 256 + threadIdx.x;
    if (t >= B_ * T_) return;
    float M1 = -1e30f, M2 = -1e30f; int J1 = -1;
    #pragma unroll
    for (int p = 0; p < 2; ++p){
        float a1 = pmax1[(long)t * 2 + p], a2 = pmax2[(long)t * 2 + p];
        int aj = pj1[(long)t * 2 + p];
        if (a1 > M1){ M2 = fmaxf(M1, a2); M1 = a1; J1 = aj; }
        else M2 = fmaxf(M2, a1);
    }
    node_idx[t] = J1;
    int i = t & (T_ - 1);
    if (i != 0 && (M1 - M2) < TAU){
        int p = atomicAdd(flagcnt, 1);
        flaglist[p] = t;
    }
}

// ---------------- fp64 exact rescore of flagged rows ----------------
__global__ __launch_bounds__(256) void exact_k(const float* __restrict__ hs,
                                               const double* __restrict__ nsq,
                                               const int* __restrict__ flagcnt,
                                               const int* __restrict__ flaglist,
                                               int* __restrict__ node_idx){
    __shared__ float arow[D_];
    __shared__ double wbv[4];
    __shared__ int wbj[4];
    int nf = *flagcnt;
    for (int f = blockIdx.x; f < nf; f += gridDim.x){
        __syncthreads();
        int t = flaglist[f];
        int b = t >> 9, i = t & 511;
        for (int d = threadIdx.x; d < D_; d += 256)
            arow[d] = hs[((long)b * L_ + 2 * i) * D_ + d];
        __syncthreads();
        int wv = threadIdx.x >> 6, lane = threadIdx.x & 63;
        double bv = -1e300; int bj = -1;
        for (int j = wv; j < T_; j += 4){
            const float* brow = hs + ((long)b * L_ + 2 * j + 1) * D_;
            double s = 0.0;
            #pragma unroll
            for (int dd = 0; dd < 12; ++dd){
                int d = dd * 64 + lane;
                s += (double)arow[d] * (double)brow[d];
            }
            #pragma unroll
            for (int off = 32; off; off >>= 1) s += __shfl_xor(s, off);
            double sc = s / sqrt(nsq[(long)b * L_ + 2 * j + 1]);
            if (sc > bv){ bv = sc; bj = j; }
        }
        if (lane == 0){ wbv[wv] = bv; wbj[wv] = bj; }
        __syncthreads();
        if (threadIdx.x == 0){
            double BV = -1e300; int BJ = 1 << 30;
            #pragma unroll
            for (int w2 = 0; w2 < 4; ++w2)
                if (wbv[w2] > BV || (wbv[w2] == BV && wbj[w2] < BJ)){ BV = wbv[w2]; BJ = wbj[w2]; }
            node_idx[t] = BJ;
        }
        __syncthreads();
    }
}

// ---------------- deterministic CSR (stable by source index) ----------------
__global__ __launch_bounds__(512) void csr_k(const int* __restrict__ node_idx,
                                             int* __restrict__ goff,
                                             int* __restrict__ glist){
    __shared__ int sidx[512];
    __shared__ int off[513];
    __shared__ int tmp[512];
    int b = blockIdx.x, t = threadIdx.x;
    sidx[t] = node_idx[b * T_ + t];
    __shared__ int cnt[512];
    cnt[t] = 0;
    __syncthreads();
    if (t >= 1) atomicAdd(&cnt[sidx[t]], 1);
    __syncthreads();
    tmp[t] = cnt[t];
    __syncthreads();
    for (int s = 1; s < 512; s <<= 1){
        int v = (t >= s) ? tmp[t - s] : 0;
        __syncthreads();
        tmp[t] += v;
        __syncthreads();
    }
    if (t == 0) off[0] = 0;
    off[t + 1] = tmp[t];
    __syncthreads();
    if (t >= 1){
        int j = sidx[t], r = 0;
        for (int i2 = 1; i2 < t; ++i2) r += (sidx[i2] == j);
        glist[b * T_ + off[j] + r] = t;
    }
    goff[b * 513 + t] = off[t];
    if (t == 0) goff[b * 513 + 512] = off[512];
}

// ---------------- merge: gather sources per dst, mean, write (+mask) ----------------
__global__ __launch_bounds__(256) void merge_k(const float* __restrict__ hs,
                                               const int* __restrict__ goff,
                                               const int* __restrict__ glist,
                                               float* __restrict__ out){
    int bid = blockIdx.x;
    int b = bid / DT_, jj = bid - b * DT_;
    long obase = ((long)b * DT_ + jj) * D_;
    if (threadIdx.x == 0) out[(long)B_ * DT_ * D_ + b * DT_ + jj] = 0.0f;  // mask
    int d0 = threadIdx.x, d1 = d0 + 256, d2 = d0 + 512;
    if (jj == 0){
        const float* src = hs + (long)b * L_ * D_;
        out[obase + d0] = src[d0]; out[obase + d1] = src[d1]; out[obase + d2] = src[d2];
        return;
    }
    int j = jj - 1;
    int o0 = goff[b * 513 + j], o1 = goff[b * 513 + j + 1];
    const float* dst = hs + ((long)b * L_ + 2 * j + 1) * D_;
    float a0 = dst[d0], a1 = dst[d1], a2 = dst[d2];
    for (int s = o0; s < o1; ++s){
        int i = glist[b * T_ + s];
        const float* srow = hs + ((long)b * L_ + 2 * i) * D_;
        a0 += srow[d0]; a1 += srow[d1]; a2 += srow[d2];
    }
    float cnt = (float)(o1 - o0 + 1);
    out[obase + d0] = a0 / cnt;
    out[obase + d1] = a1 / cnt;
    out[obase + d2] = a2 / cnt;
}

extern "C" void kernel_launch(void* const* d_in, const int* in_sizes, int n_in,
                              void* d_out, int out_size, void* d_ws, size_t ws_size,
                              hipStream_t stream){
    const float* hs = (const float*)d_in[0];  // (128,1024,768) f32
    float* out = (float*)d_out;
    char* ws = (char*)d_ws;

    // packed B (hi/lo) lives in d_out as scratch until merge_k overwrites it:
    unsigned short* Bh = (unsigned short*)d_out;
    unsigned short* Bl = Bh + (long)B_ * CH_ * T_ * 8;   // 201.3 MB total <= 202 MB

    float*  rnorm    = (float*) (ws + 0);         // 524288 B  (even entries valid)
    double* nsq      = (double*)(ws + 524288);    // 1048576 B (odd entries valid)
    float*  pmax1    = (float*) (ws + 1572864);   // 524288 B
    int*    pj1      = (int*)   (ws + 2097152);   // 524288 B
    float*  pmax2    = (float*) (ws + 2621440);   // 524288 B
    int*    node_idx = (int*)   (ws + 3145728);   // 262144 B
    int*    flagcnt  = (int*)   (ws + 3407872);   // 256 B
    int*    flaglist = (int*)   (ws + 3408128);   // 262144 B
    int*    goff     = (int*)   (ws + 3670272);   // 263168 B
    int*    glist    = (int*)   (ws + 3933440);   // 262144 B

    norms_k <<<B_ * T_ / 4, 256, 0, stream>>>(hs, rnorm, flagcnt);
    pack_k  <<<B_ * 32, 256, 0, stream>>>(hs, Bh, Bl, nsq);
    scores_k<<<B_ * 16, 256, 0, stream>>>(hs, rnorm, Bh, Bl, pmax1, pj1, pmax2);
    reduce_k<<<B_ * T_ / 256, 256, 0, stream>>>(pmax1, pj1, pmax2, node_idx, flagcnt, flaglist);
    exact_k <<<256, 256, 0, stream>>>(hs, nsq, flagcnt, flaglist, node_idx);
    csr_k   <<<B_, 512, 0, stream>>>(node_idx, goff, glist);
    merge_k <<<B_ * DT_, 256, 0, stream>>>(hs, goff, glist, out);
}